// Round 8
// baseline (383.545 us; speedup 1.0000x reference)
//
#include <hip/hip_runtime.h>
#include <math.h>

typedef __attribute__((ext_vector_type(8))) short short8;
typedef __attribute__((ext_vector_type(4))) float floatx4;

static __device__ __forceinline__ ushort f32_to_bf16_rne(float f) {
  union { float f; unsigned int i; } c;
  c.f = f;
  unsigned int lsb = (c.i >> 16) & 1u;
  c.i += 0x7fffu + lsb;
  return (ushort)(c.i >> 16);
}
static __device__ __forceinline__ float bf16_lo(unsigned int v) {
  union { unsigned int i; float f; } c;
  c.i = v << 16;
  return c.f;
}
static __device__ __forceinline__ float bf16_hi(unsigned int v) {
  union { unsigned int i; float f; } c;
  c.i = v & 0xffff0000u;
  return c.f;
}

// ---------------- graph build v3: block-local sort -> coalesced binned2 -> bucket build ------
// bucket = dst >> 9 (512 nodes). NBLK=256 edge chunks of EBLK edges.
// binned2: block-major; block blk's edges sorted by bucket at [blk*EBLK ...].
// bh2[b][blk] (b=0..196): local exclusive start of bucket b within block blk's run
//   (row 196 = sentinel: run length). record: u32 = (dst&511)<<17 | src  (needs N < 2^17).

#define NBLK 256
#define MAXPER 26  // ceil(EBLK/256); valid for E <= 1,703,936

__global__ __launch_bounds__(256) void binsort_kernel(const int* __restrict__ src,
                                                      const int* __restrict__ dst,
                                                      int* __restrict__ bh2,
                                                      unsigned int* __restrict__ binned2, int E,
                                                      int EBLK, int NBUCKET) {
  __shared__ int h[256];       // histogram
  __shared__ int lstart[256];  // exclusive starts (preserved)
  __shared__ int cursor[256];  // scatter cursors
  __shared__ int sd[256];
  __shared__ unsigned int sorted[6272];
  int t = threadIdx.x, blk = blockIdx.x;
  int e0 = blk * EBLK, e1 = min(E, e0 + EBLK);
  int ds[MAXPER], ss[MAXPER];
  int cnt = 0;
  h[t] = 0;
  __syncthreads();
#pragma unroll
  for (int i = 0; i < MAXPER; i++) {
    int e = e0 + t + i * 256;
    if (e < e1) {
      ds[i] = __builtin_nontemporal_load(dst + e);
      ss[i] = __builtin_nontemporal_load(src + e);
      atomicAdd(&h[ds[i] >> 9], 1);
      cnt = i + 1;
    }
  }
  __syncthreads();
  int v = h[t];
  sd[t] = v;
  __syncthreads();
  int acc = v;
  for (int off = 1; off < 256; off <<= 1) {
    int add = (t >= off) ? sd[t - off] : 0;
    __syncthreads();
    acc += add;
    sd[t] = acc;
    __syncthreads();
  }
  int start = acc - v;  // exclusive
  lstart[t] = start;
  cursor[t] = start;
  if (t < NBUCKET) bh2[t * NBLK + blk] = start;
  if (t == 0) bh2[NBUCKET * NBLK + blk] = e1 - e0;  // sentinel row
  __syncthreads();
#pragma unroll
  for (int i = 0; i < MAXPER; i++) {
    if (i < cnt) {
      int d = ds[i];
      int pos = atomicAdd(&cursor[d >> 9], 1);
      sorted[pos] = ((unsigned int)(d & 511) << 17) | (unsigned int)ss[i];
    }
  }
  __syncthreads();
  int n = e1 - e0;
  for (int i = t; i < n; i += 256) binned2[(size_t)e0 + i] = sorted[i];
}

// single block: bucket totals from bh2 row-diffs, exclusive scan -> bucketStart
__global__ void bucketscan_kernel(const int* __restrict__ bh2, int* __restrict__ bucketStart,
                                  int NBUCKET) {
  __shared__ int sd[256];
  int t = threadIdx.x;
  int tot = 0;
  if (t < NBUCKET) {
    const int* r0 = bh2 + (size_t)t * NBLK;
    const int* r1 = bh2 + (size_t)(t + 1) * NBLK;
#pragma unroll 8
    for (int i = 0; i < NBLK; i++) tot += r1[i] - r0[i];
  }
  sd[t] = tot;
  __syncthreads();
  int acc = tot;
  for (int off = 1; off < 256; off <<= 1) {
    int add = (t >= off) ? sd[t - off] : 0;
    __syncthreads();
    acc += add;
    sd[t] = acc;
    __syncthreads();
  }
  if (t < NBUCKET) bucketStart[t] = acc - tot;
}

// one block per bucket: gather 256 segments (binary-search addressing), LDS node hist,
// scan 512, write offcnt, scatter csr (second read is L2-hot: 32KB window).
__global__ __launch_bounds__(256) void bucket_build2_kernel(
    const unsigned int* __restrict__ binned2, const int* __restrict__ bh2,
    const int* __restrict__ bucketStart, int2* __restrict__ offcnt, int* __restrict__ csr, int N,
    int EBLK, int NBUCKET) {
  __shared__ int ls0[256];
  __shared__ int dof[257];
  __shared__ int h[512];
  __shared__ int cur[512];
  __shared__ int sd[256];
  int b = blockIdx.x, t = threadIdx.x;
  int l0 = bh2[(size_t)b * NBLK + t];
  int l1 = bh2[(size_t)(b + 1) * NBLK + t];
  int len = l1 - l0;
  ls0[t] = l0;
  sd[t] = len;
  __syncthreads();
  int acc = len;
  for (int off = 1; off < 256; off <<= 1) {
    int add = (t >= off) ? sd[t - off] : 0;
    __syncthreads();
    acc += add;
    sd[t] = acc;
    __syncthreads();
  }
  dof[t] = acc - len;
  if (t == 255) dof[256] = acc;
  h[t] = 0;
  h[t + 256] = 0;
  __syncthreads();
  int tot = dof[256];
  int S = bucketStart[b];
  // phase B: histogram
  for (int i = t; i < tot; i += 256) {
    int lo = 0, hi = 255;
    while (lo < hi) {
      int mid = (lo + hi + 1) >> 1;
      if (dof[mid] <= i) lo = mid; else hi = mid - 1;
    }
    unsigned int rv = binned2[(size_t)lo * EBLK + ls0[lo] + (i - dof[lo])];
    atomicAdd(&h[(rv >> 17) & 511], 1);
  }
  __syncthreads();
  int h0 = h[2 * t], h1 = h[2 * t + 1];
  int s2 = h0 + h1;
  sd[t] = s2;
  __syncthreads();
  int a2 = s2;
  for (int off = 1; off < 256; off <<= 1) {
    int add = (t >= off) ? sd[t - off] : 0;
    __syncthreads();
    a2 += add;
    sd[t] = a2;
    __syncthreads();
  }
  int run = a2 - s2;
  int node0 = b * 512;
  {
    int l = 2 * t;
    int node = node0 + l;
    int st = S + run;
    if (node < N) offcnt[node] = make_int2(st, h0);
    cur[l] = st;
    l = 2 * t + 1;
    node = node0 + l;
    st = S + run + h0;
    if (node < N) offcnt[node] = make_int2(st, h1);
    cur[l] = st;
  }
  __syncthreads();
  // phase C: scatter (re-read, L2-hot)
  for (int i = t; i < tot; i += 256) {
    int lo = 0, hi = 255;
    while (lo < hi) {
      int mid = (lo + hi + 1) >> 1;
      if (dof[mid] <= i) lo = mid; else hi = mid - 1;
    }
    unsigned int rv = binned2[(size_t)lo * EBLK + ls0[lo] + (i - dof[lo])];
    int pos = atomicAdd(&cur[(rv >> 17) & 511], 1);
    csr[pos] = (int)(rv & 0x1ffffu);
  }
}

// ---------------- conversions ----------------

__global__ void f32_to_bf16_kernel(const float* __restrict__ in, ushort* __restrict__ out, int n) {
  int i = (blockIdx.x * 256 + threadIdx.x) * 8;
  if (i >= n) return;
  float4 a = *(const float4*)(in + i);
  float4 b = *(const float4*)(in + i + 4);
  union { ushort u[8]; short8 v; } r;
  r.u[0] = f32_to_bf16_rne(a.x); r.u[1] = f32_to_bf16_rne(a.y);
  r.u[2] = f32_to_bf16_rne(a.z); r.u[3] = f32_to_bf16_rne(a.w);
  r.u[4] = f32_to_bf16_rne(b.x); r.u[5] = f32_to_bf16_rne(b.y);
  r.u[6] = f32_to_bf16_rne(b.z); r.u[7] = f32_to_bf16_rne(b.w);
  *(short8*)(out + i) = r.v;
}

// all four weight transposes in one launch. WT[c][k] = bf16(W[k][c]), K=128 always.
__global__ void wt_conv_all_kernel(const float* __restrict__ Wl1, const float* __restrict__ Wr1,
                                   const float* __restrict__ Wl2, const float* __restrict__ Wr2,
                                   ushort* __restrict__ WlT1, ushort* __restrict__ WrT1,
                                   ushort* __restrict__ WlT2, ushort* __restrict__ WrT2) {
  int idx = blockIdx.x * 256 + threadIdx.x;  // 0..49151
  const float* W;
  ushort* WT;
  int C, base;
  if (idx < 16384)      { W = Wl1; WT = WlT1; C = 128; base = idx; }
  else if (idx < 32768) { W = Wr1; WT = WrT1; C = 128; base = idx - 16384; }
  else if (idx < 40960) { W = Wl2; WT = WlT2; C = 64;  base = idx - 32768; }
  else                  { W = Wr2; WT = WrT2; C = 64;  base = idx - 40960; }
  int k = base / C, c = base % C;
  WT[c * 128 + k] = f32_to_bf16_rne(W[base]);
}

// ---------------- aggregation: segment max (bf16 rows, 256B each) ----------------
// one wave per node; lane owns 2 bf16 dims packed in one u32.
// node/start/deg/csr wave-uniform via readfirstlane -> scalar path (s_load index stream,
// saddr-form feature gathers, SALU loop control).

__global__ __launch_bounds__(256) void agg_max_bf16_kernel(
    const ushort* __restrict__ feat, const int* __restrict__ csr,
    const int2* __restrict__ offcnt, unsigned int* __restrict__ aggb, int N) {
  int lane = threadIdx.x & 63;
  int node = __builtin_amdgcn_readfirstlane((int)((blockIdx.x * 256 + threadIdx.x) >> 6));
  if (node >= N) return;
  const unsigned int* fu = (const unsigned int*)feat;
  int2 oc = offcnt[node];
  int start = oc.x;
  int deg = oc.y;
  float m0 = 0.0f, m1 = 0.0f;  // PyG scatter-max: 0 for isolated nodes
  if (deg > 0) {
    m0 = -INFINITY;
    m1 = -INFINITY;
    const int* ce = csr + start;
    int e = 0;
    for (; e + 8 <= deg; e += 8) {
      int s0 = ce[e + 0], s1 = ce[e + 1], s2 = ce[e + 2], s3 = ce[e + 3];
      int s4 = ce[e + 4], s5 = ce[e + 5], s6 = ce[e + 6], s7 = ce[e + 7];
      unsigned int v0 = fu[(size_t)s0 * 64 + lane];
      unsigned int v1 = fu[(size_t)s1 * 64 + lane];
      unsigned int v2 = fu[(size_t)s2 * 64 + lane];
      unsigned int v3 = fu[(size_t)s3 * 64 + lane];
      unsigned int v4 = fu[(size_t)s4 * 64 + lane];
      unsigned int v5 = fu[(size_t)s5 * 64 + lane];
      unsigned int v6 = fu[(size_t)s6 * 64 + lane];
      unsigned int v7 = fu[(size_t)s7 * 64 + lane];
      m0 = fmaxf(m0, fmaxf(fmaxf(bf16_lo(v0), bf16_lo(v1)), fmaxf(bf16_lo(v2), bf16_lo(v3))));
      m0 = fmaxf(m0, fmaxf(fmaxf(bf16_lo(v4), bf16_lo(v5)), fmaxf(bf16_lo(v6), bf16_lo(v7))));
      m1 = fmaxf(m1, fmaxf(fmaxf(bf16_hi(v0), bf16_hi(v1)), fmaxf(bf16_hi(v2), bf16_hi(v3))));
      m1 = fmaxf(m1, fmaxf(fmaxf(bf16_hi(v4), bf16_hi(v5)), fmaxf(bf16_hi(v6), bf16_hi(v7))));
    }
    for (; e < deg; e++) {
      unsigned int v = fu[(size_t)ce[e] * 64 + lane];
      m0 = fmaxf(m0, bf16_lo(v));
      m1 = fmaxf(m1, bf16_hi(v));
    }
  }
  // m0/m1 are exact bf16 values (or 0) -> truncation is exact
  unsigned int res = (__float_as_uint(m0) >> 16) | (__float_as_uint(m1) & 0xffff0000u);
  aggb[(size_t)node * 64 + lane] = res;
}

// ---------------- fused dual-GEMM (MFMA bf16) + bias + L2 normalize (+ ReLU) ----------------
// Row-major bf16 A/X [N][128]; WT[c][k] transposed weights. No LDS.
// A frags: lane&15 = row, lane>>4 = k-octet. C/D: col=ct*16+l16, row=rt*16+lk*4+reg.

template <int DOUT, bool RELU, bool OUTBF16>
__global__ __launch_bounds__(256) void gemm_mfma_kernel(
    const ushort* __restrict__ A, const ushort* __restrict__ X, const ushort* __restrict__ WlT,
    const ushort* __restrict__ WrT, const float* __restrict__ bias, void* __restrict__ outp,
    int N) {
  constexpr int D = 128;
  constexpr int NCT = DOUT / 16;
  int t = threadIdx.x;
  int lane = t & 63;
  int wid = t >> 6;
  int l16 = lane & 15;
  int lk = lane >> 4;
  int rowbase = blockIdx.x * 128 + wid * 32;

  floatx4 acc[2][NCT];
#pragma unroll
  for (int rt = 0; rt < 2; rt++)
#pragma unroll
    for (int ct = 0; ct < NCT; ct++) acc[rt][ct] = (floatx4){0.f, 0.f, 0.f, 0.f};

  int ra = rowbase + l16;       if (ra > N - 1) ra = N - 1;
  int rb = rowbase + 16 + l16;  if (rb > N - 1) rb = N - 1;
  const ushort* pA0 = A + (size_t)ra * D;
  const ushort* pA1 = A + (size_t)rb * D;
  const ushort* pX0 = X + (size_t)ra * D;
  const ushort* pX1 = X + (size_t)rb * D;

#pragma unroll
  for (int kc = 0; kc < 4; kc++) {
    int ko = kc * 32 + lk * 8;
    short8 a0 = *(const short8*)(pA0 + ko);
    short8 a1 = *(const short8*)(pA1 + ko);
    short8 x0 = *(const short8*)(pX0 + ko);
    short8 x1 = *(const short8*)(pX1 + ko);
#pragma unroll
    for (int ct = 0; ct < NCT; ct++) {
      int c = ct * 16 + l16;
      short8 bl = *(const short8*)(WlT + (size_t)c * D + ko);
      short8 br = *(const short8*)(WrT + (size_t)c * D + ko);
      acc[0][ct] = __builtin_amdgcn_mfma_f32_16x16x32_bf16(a0, bl, acc[0][ct], 0, 0, 0);
      acc[0][ct] = __builtin_amdgcn_mfma_f32_16x16x32_bf16(x0, br, acc[0][ct], 0, 0, 0);
      acc[1][ct] = __builtin_amdgcn_mfma_f32_16x16x32_bf16(a1, bl, acc[1][ct], 0, 0, 0);
      acc[1][ct] = __builtin_amdgcn_mfma_f32_16x16x32_bf16(x1, br, acc[1][ct], 0, 0, 0);
    }
  }

  float bb[NCT];
#pragma unroll
  for (int ct = 0; ct < NCT; ct++) bb[ct] = bias[ct * 16 + l16];
#pragma unroll
  for (int rt = 0; rt < 2; rt++)
#pragma unroll
    for (int ct = 0; ct < NCT; ct++)
#pragma unroll
      for (int r = 0; r < 4; r++) acc[rt][ct][r] += bb[ct];

#pragma unroll
  for (int rt = 0; rt < 2; rt++) {
#pragma unroll
    for (int r = 0; r < 4; r++) {
      float ss = 0.f;
#pragma unroll
      for (int ct = 0; ct < NCT; ct++) ss += acc[rt][ct][r] * acc[rt][ct][r];
      ss += __shfl_xor(ss, 1);
      ss += __shfl_xor(ss, 2);
      ss += __shfl_xor(ss, 4);
      ss += __shfl_xor(ss, 8);
      float inv = 1.0f / fmaxf(sqrtf(ss), 1e-12f);
      int n = rowbase + rt * 16 + lk * 4 + r;
      if (n < N) {
#pragma unroll
        for (int ct = 0; ct < NCT; ct++) {
          float v = acc[rt][ct][r] * inv;
          if (RELU) v = fmaxf(v, 0.f);
          size_t o = (size_t)n * DOUT + ct * 16 + l16;
          if (OUTBF16)
            ((ushort*)outp)[o] = f32_to_bf16_rne(v);
          else
            ((float*)outp)[o] = v;
        }
      }
    }
  }
}

// ---------------- launch ----------------

extern "C" void kernel_launch(void* const* d_in, const int* in_sizes, int n_in, void* d_out,
                              int out_size, void* d_ws, size_t ws_size, hipStream_t stream) {
  const float* x = (const float*)d_in[0];
  const int* ei = (const int*)d_in[1];
  const float* Wl1 = (const float*)d_in[2];
  const float* Wr1 = (const float*)d_in[3];
  const float* b1 = (const float*)d_in[4];
  const float* Wl2 = (const float*)d_in[5];
  const float* Wr2 = (const float*)d_in[6];
  const float* b2 = (const float*)d_in[7];
  float* out = (float*)d_out;

  const int E = in_sizes[1] / 2;
  const int N = in_sizes[0] / 128;
  const int D = 128;

  const int* src = ei;
  const int* dst = ei + E;

  char* w = (char*)d_ws;
  size_t off = 0;
  auto alloc = [&](size_t bytes) {
    void* p = w + off;
    off = (off + bytes + 511) & ~((size_t)511);
    return p;
  };
  const int NBUCKET = (N + 511) >> 9;  // 196
  int* bh2 = (int*)alloc((size_t)(NBUCKET + 1) * NBLK * 4);
  int* bucketStart = (int*)alloc((size_t)NBUCKET * 4);
  int2* offcnt = (int2*)alloc((size_t)N * 8);
  unsigned int* binned2 = (unsigned int*)alloc((size_t)E * 4);
  int* csr = (int*)alloc((size_t)E * 4);
  ushort* xb = (ushort*)alloc((size_t)N * D * 2);
  ushort* aggb = (ushort*)alloc((size_t)N * D * 2);
  ushort* hb = (ushort*)alloc((size_t)N * D * 2);
  ushort* WlT1 = (ushort*)alloc(128 * 128 * 2);
  ushort* WrT1 = (ushort*)alloc(128 * 128 * 2);
  ushort* WlT2 = (ushort*)alloc(128 * 64 * 2);
  ushort* WrT2 = (ushort*)alloc(128 * 64 * 2);
  (void)ws_size;

  const int EBLK = (E + NBLK - 1) / NBLK;  // 6250; must be <= MAXPER*256

  // graph build (reused by both layers)
  binsort_kernel<<<NBLK, 256, 0, stream>>>(src, dst, bh2, binned2, E, EBLK, NBUCKET);
  bucketscan_kernel<<<1, 256, 0, stream>>>(bh2, bucketStart, NBUCKET);
  bucket_build2_kernel<<<NBUCKET, 256, 0, stream>>>(binned2, bh2, bucketStart, offcnt, csr, N,
                                                    EBLK, NBUCKET);

  // conversions
  f32_to_bf16_kernel<<<(N * D / 8 + 255) / 256, 256, 0, stream>>>(x, xb, N * D);
  wt_conv_all_kernel<<<192, 256, 0, stream>>>(Wl1, Wr1, Wl2, Wr2, WlT1, WrT1, WlT2, WrT2);

  const int nbGemm = (N + 127) / 128;

  // layer 1
  agg_max_bf16_kernel<<<(N * 64 + 255) / 256, 256, 0, stream>>>(xb, csr, offcnt,
                                                                (unsigned int*)aggb, N);
  gemm_mfma_kernel<128, true, true>
      <<<nbGemm, 256, 0, stream>>>(aggb, xb, WlT1, WrT1, b1, hb, N);

  // layer 2
  agg_max_bf16_kernel<<<(N * 64 + 255) / 256, 256, 0, stream>>>(hb, csr, offcnt,
                                                                (unsigned int*)aggb, N);
  gemm_mfma_kernel<64, false, false>
      <<<nbGemm, 256, 0, stream>>>(aggb, hb, WlT2, WrT2, b2, out, N);
}